// Round 1
// baseline (1219.566 us; speedup 1.0000x reference)
//
#include <hip/hip_runtime.h>
#include <math.h>

#define SS 2304
#define C_IN 256
#define HID 512
#define QKV3 1536
#define HEADS 8
#define DH 64
#define BATCH 4
#define EPSV 1e-5f
#define SCALEV 0.125f

// ---------------- prep: wg = w_qkv * g, wsum[o] = sum_c wg ----------------
__global__ void prep_wg(const float* __restrict__ w, const float* __restrict__ g,
                        float* __restrict__ wg, float* __restrict__ wsum) {
    __shared__ float red[256];
    int o = blockIdx.x, c = threadIdx.x;
    float v = w[o * C_IN + c] * g[c];
    wg[o * C_IN + c] = v;
    red[c] = v;
    __syncthreads();
    for (int st = 128; st > 0; st >>= 1) {
        if (c < st) red[c] += red[c + st];
        __syncthreads();
    }
    if (c == 0) wsum[o] = red[0];
}

// ---------------- prep: RoPE tables in double precision ----------------
__global__ void prep_rope(float* __restrict__ cosT, float* __restrict__ sinT) {
    int idx = blockIdx.x * 256 + threadIdx.x;
    if (idx >= SS * 32) return;
    int s = idx >> 5, f = idx & 31;
    double inv = pow(10000.0, -(double)f / 32.0);
    double ang = (double)s * inv;
    cosT[idx] = (float)cos(ang);
    sinT[idx] = (float)sin(ang);
}

// ---------------- prep: per-pixel mean / rstd over C ----------------
__global__ void prep_stats(const float* __restrict__ x, float* __restrict__ mean,
                           float* __restrict__ rstd) {
    int p = blockIdx.x * 256 + threadIdx.x;  // 0..9215
    int b = p / SS, s = p % SS;
    const float* xp = x + (size_t)b * C_IN * SS + s;
    float sm = 0.f;
    for (int c = 0; c < C_IN; ++c) sm += xp[(size_t)c * SS];
    float mu = sm * (1.0f / C_IN);
    float vs = 0.f;
    for (int c = 0; c < C_IN; ++c) { float d = xp[(size_t)c * SS] - mu; vs += d * d; }
    mean[p] = mu;
    rstd[p] = rsqrtf(vs * (1.0f / C_IN) + EPSV);
}

// ---------------- QKV GEMM with folded layernorm ----------------
// qkv[b][o][s] = rstd * (sum_c wg[o][c]*x[b][c][s] - mean*wsum[o])
__global__ __launch_bounds__(256) void qkv_gemm(
    const float* __restrict__ x, const float* __restrict__ wg,
    const float* __restrict__ wsum, const float* __restrict__ mean,
    const float* __restrict__ rstd, float* __restrict__ qkv) {
    __shared__ float As[16][132];
    __shared__ float Bs[16][132];
    int b = blockIdx.z;
    int m0 = blockIdx.y * 128;
    int n0 = blockIdx.x * 128;
    int t = threadIdx.x;
    int tx = t & 15, ty = t >> 4;
    float acc[8][8] = {};
    const float* xb = x + (size_t)b * C_IN * SS;
    for (int k0 = 0; k0 < C_IN; k0 += 16) {
#pragma unroll
        for (int i = 0; i < 8; ++i) {
            int idx = t + i * 256;
            int kk = idx & 15, row = idx >> 4;
            As[kk][row] = wg[(m0 + row) * C_IN + k0 + kk];
            int ssi = idx & 127, cc = idx >> 7;
            Bs[cc][ssi] = xb[(size_t)(k0 + cc) * SS + n0 + ssi];
        }
        __syncthreads();
#pragma unroll
        for (int kk = 0; kk < 16; ++kk) {
            float4 a0 = *(const float4*)&As[kk][ty * 8];
            float4 a1 = *(const float4*)&As[kk][ty * 8 + 4];
            float4 b0 = *(const float4*)&Bs[kk][tx * 8];
            float4 b1 = *(const float4*)&Bs[kk][tx * 8 + 4];
            float am[8] = {a0.x, a0.y, a0.z, a0.w, a1.x, a1.y, a1.z, a1.w};
            float bn[8] = {b0.x, b0.y, b0.z, b0.w, b1.x, b1.y, b1.z, b1.w};
#pragma unroll
            for (int r = 0; r < 8; ++r)
#pragma unroll
                for (int c = 0; c < 8; ++c) acc[r][c] += am[r] * bn[c];
        }
        __syncthreads();
    }
    float mnv[8], rsv[8];
#pragma unroll
    for (int c = 0; c < 8; ++c) {
        int n = n0 + tx * 8 + c;
        mnv[c] = mean[b * SS + n];
        rsv[c] = rstd[b * SS + n];
    }
#pragma unroll
    for (int r = 0; r < 8; ++r) {
        int m = m0 + ty * 8 + r;
        float ws = wsum[m];
        float* dst = qkv + ((size_t)b * QKV3 + m) * SS + n0 + tx * 8;
        float ov[8];
#pragma unroll
        for (int c = 0; c < 8; ++c) ov[c] = rsv[c] * (acc[r][c] - mnv[c] * ws);
        *(float4*)dst = make_float4(ov[0], ov[1], ov[2], ov[3]);
        *(float4*)(dst + 4) = make_float4(ov[4], ov[5], ov[6], ov[7]);
    }
}

// ---------------- dwconv 3x3 + transpose to (B,H,S,D) + RoPE (+scale q) ----------------
__global__ __launch_bounds__(256) void conv_rope(
    const float* __restrict__ qkv, const float* __restrict__ dwq,
    const float* __restrict__ dwk, const float* __restrict__ dwv,
    const float* __restrict__ cosT, const float* __restrict__ sinT,
    float* __restrict__ seq) {
    __shared__ float tile[64][65];
    int b = blockIdx.z;
    int part = blockIdx.y >> 3;
    int h = blockIdx.y & 7;
    int s0 = blockIdx.x * 64;
    int t = threadIdx.x;
    int sl = t & 63, dgrp = t >> 6;
    int s = s0 + sl;
    int y = s / 48, xx = s - y * 48;
    const float* dw = (part == 0) ? dwq : (part == 1) ? dwk : dwv;
#pragma unroll
    for (int i = 0; i < 16; ++i) {
        int d = dgrp * 16 + i;
        int cch = part * HID + h * DH + d;
        const float* src = qkv + ((size_t)b * QKV3 + cch) * SS;
        const float* wp = dw + (h * DH + d) * 9;
        float acc = 0.f;
#pragma unroll
        for (int dy = -1; dy <= 1; ++dy) {
            int yy = y + dy;
            if (yy < 0 || yy >= 48) continue;
#pragma unroll
            for (int dx = -1; dx <= 1; ++dx) {
                int xv = xx + dx;
                if (xv < 0 || xv >= 48) continue;
                acc += wp[(dy + 1) * 3 + (dx + 1)] * src[yy * 48 + xv];
            }
        }
        tile[d][sl] = acc;
    }
    __syncthreads();
    int d2 = t & 63, srow = t >> 6;
    float* outb = seq + ((size_t)part * BATCH * HEADS + (size_t)b * HEADS + h) * SS * DH;
#pragma unroll
    for (int i = 0; i < 16; ++i) {
        int sp = srow + 4 * i;
        float v0 = tile[d2][sp];
        float val;
        if (part < 2) {
            float vp = tile[d2 ^ 32][sp];
            int f = d2 & 31;
            float cv = cosT[(s0 + sp) * 32 + f];
            float sv = sinT[(s0 + sp) * 32 + f];
            float rot = (d2 < 32) ? -vp : vp;
            val = v0 * cv + rot * sv;
            if (part == 0) val *= SCALEV;
        } else {
            val = v0;
        }
        outb[(size_t)(s0 + sp) * DH + d2] = val;
    }
}

// ---------------- flash attention, fp32, online softmax ----------------
__global__ __launch_bounds__(256) void attn(const float* __restrict__ seq,
                                            float* __restrict__ O) {
    __shared__ float qT[64][66];
    __shared__ float kT[64][66];
    __shared__ float vS[64][66];
    __shared__ float pT[64][66];
    __shared__ float red[64][17];
    __shared__ float m_s[64], l_s[64], a_s[64];
    int bh = blockIdx.y;
    int i0 = blockIdx.x * 64;
    int t = threadIdx.x;
    int tx = t & 15, ty = t >> 4;
    const size_t P = (size_t)BATCH * HEADS * SS * DH;
    const float* q = seq + (size_t)bh * SS * DH;
    const float* k = q + P;
    const float* v = q + 2 * P;
#pragma unroll
    for (int i = 0; i < 16; ++i) {
        int idx = t + i * 256;
        int dd = idx & 63, ii = idx >> 6;
        qT[dd][ii] = q[(size_t)(i0 + ii) * DH + dd];
    }
    if (t < 64) { m_s[t] = -INFINITY; l_s[t] = 0.f; }
    float o_acc[4][4] = {};
    __syncthreads();
    for (int jt = 0; jt < 36; ++jt) {
        int j0 = jt * 64;
#pragma unroll
        for (int i = 0; i < 16; ++i) {
            int idx = t + i * 256;
            int dd = idx & 63, jj = idx >> 6;
            float kvv = k[(size_t)(j0 + jj) * DH + dd];
            float vvv = v[(size_t)(j0 + jj) * DH + dd];
            kT[dd][jj] = kvv;
            vS[jj][dd] = vvv;
        }
        __syncthreads();
        float sa[4][4] = {};
#pragma unroll 8
        for (int dd = 0; dd < 64; ++dd) {
            float qa[4], ka[4];
            { float2 u = *(const float2*)&qT[dd][ty * 4];
              float2 w2 = *(const float2*)&qT[dd][ty * 4 + 2];
              qa[0] = u.x; qa[1] = u.y; qa[2] = w2.x; qa[3] = w2.y; }
            { float2 u = *(const float2*)&kT[dd][tx * 4];
              float2 w2 = *(const float2*)&kT[dd][tx * 4 + 2];
              ka[0] = u.x; ka[1] = u.y; ka[2] = w2.x; ka[3] = w2.y; }
#pragma unroll
            for (int r = 0; r < 4; ++r)
#pragma unroll
                for (int c = 0; c < 4; ++c) sa[r][c] += qa[r] * ka[c];
        }
#pragma unroll
        for (int r = 0; r < 4; ++r) {
            float rm = fmaxf(fmaxf(sa[r][0], sa[r][1]), fmaxf(sa[r][2], sa[r][3]));
            red[ty * 4 + r][tx] = rm;
        }
        __syncthreads();
        if (t < 64) {
            float mt = red[t][0];
#pragma unroll
            for (int x2 = 1; x2 < 16; ++x2) mt = fmaxf(mt, red[t][x2]);
            float mo = m_s[t];
            float mn = fmaxf(mo, mt);
            float al = expf(mo - mn);
            a_s[t] = al;
            m_s[t] = mn;
            l_s[t] *= al;
        }
        __syncthreads();
#pragma unroll
        for (int r = 0; r < 4; ++r) {
            int irow = ty * 4 + r;
            float al = a_s[irow];
#pragma unroll
            for (int c = 0; c < 4; ++c) o_acc[r][c] *= al;
            float mn = m_s[irow];
            float p0 = expf(sa[r][0] - mn), p1 = expf(sa[r][1] - mn);
            float p2 = expf(sa[r][2] - mn), p3 = expf(sa[r][3] - mn);
            pT[tx * 4 + 0][irow] = p0;
            pT[tx * 4 + 1][irow] = p1;
            pT[tx * 4 + 2][irow] = p2;
            pT[tx * 4 + 3][irow] = p3;
            red[irow][tx] = p0 + p1 + p2 + p3;
        }
        __syncthreads();
        if (t < 64) {
            float sm = red[t][0];
#pragma unroll
            for (int x2 = 1; x2 < 16; ++x2) sm += red[t][x2];
            l_s[t] += sm;
        }
#pragma unroll 8
        for (int jj = 0; jj < 64; ++jj) {
            float pa[4], va[4];
            { float2 u = *(const float2*)&pT[jj][ty * 4];
              float2 w2 = *(const float2*)&pT[jj][ty * 4 + 2];
              pa[0] = u.x; pa[1] = u.y; pa[2] = w2.x; pa[3] = w2.y; }
            { float2 u = *(const float2*)&vS[jj][tx * 4];
              float2 w2 = *(const float2*)&vS[jj][tx * 4 + 2];
              va[0] = u.x; va[1] = u.y; va[2] = w2.x; va[3] = w2.y; }
#pragma unroll
            for (int r = 0; r < 4; ++r)
#pragma unroll
                for (int c = 0; c < 4; ++c) o_acc[r][c] += pa[r] * va[c];
        }
        __syncthreads();
    }
#pragma unroll
    for (int r = 0; r < 4; ++r) {
        int i = i0 + ty * 4 + r;
        float inv = 1.f / l_s[ty * 4 + r];
        float4 ov = make_float4(o_acc[r][0] * inv, o_acc[r][1] * inv,
                                o_acc[r][2] * inv, o_acc[r][3] * inv);
        *(float4*)&O[((size_t)bh * SS + i) * DH + tx * 4] = ov;
    }
}

// ---------------- output projection + bias ----------------
__global__ __launch_bounds__(256) void outproj(
    const float* __restrict__ O, const float* __restrict__ w_out,
    const float* __restrict__ b_out, float* __restrict__ out) {
    __shared__ float As[16][68];
    __shared__ float Bs[16][132];
    int b = blockIdx.z;
    int m0 = blockIdx.y * 64;
    int n0 = blockIdx.x * 128;
    int t = threadIdx.x;
    int tx = t & 15, ty = t >> 4;
    float acc[4][8] = {};
    for (int k0 = 0; k0 < HID; k0 += 16) {
        int h = k0 >> 6, d0 = k0 & 63;
        const float* Ob = O + ((size_t)(b * HEADS + h) * SS + n0) * DH + d0;
#pragma unroll
        for (int i = 0; i < 4; ++i) {
            int idx = t + i * 256;
            int kk = idx & 15, mm = idx >> 4;
            As[kk][mm] = w_out[(m0 + mm) * HID + k0 + kk];
        }
#pragma unroll
        for (int i = 0; i < 8; ++i) {
            int idx = t + i * 256;
            int kk = idx & 15, nn = idx >> 4;
            Bs[kk][nn] = Ob[(size_t)nn * DH + kk];
        }
        __syncthreads();
#pragma unroll
        for (int kk = 0; kk < 16; ++kk) {
            float4 av = *(const float4*)&As[kk][ty * 4];
            float4 b0 = *(const float4*)&Bs[kk][tx * 8];
            float4 b1 = *(const float4*)&Bs[kk][tx * 8 + 4];
            float aa[4] = {av.x, av.y, av.z, av.w};
            float bb[8] = {b0.x, b0.y, b0.z, b0.w, b1.x, b1.y, b1.z, b1.w};
#pragma unroll
            for (int r = 0; r < 4; ++r)
#pragma unroll
                for (int c = 0; c < 8; ++c) acc[r][c] += aa[r] * bb[c];
        }
        __syncthreads();
    }
#pragma unroll
    for (int r = 0; r < 4; ++r) {
        int o = m0 + ty * 4 + r;
        float bo = b_out[o];
        float* dst = out + ((size_t)b * C_IN + o) * SS + n0 + tx * 8;
        float ov[8];
#pragma unroll
        for (int c = 0; c < 8; ++c) ov[c] = acc[r][c] + bo;
        *(float4*)dst = make_float4(ov[0], ov[1], ov[2], ov[3]);
        *(float4*)(dst + 4) = make_float4(ov[4], ov[5], ov[6], ov[7]);
    }
}

extern "C" void kernel_launch(void* const* d_in, const int* in_sizes, int n_in,
                              void* d_out, int out_size, void* d_ws, size_t ws_size,
                              hipStream_t stream) {
    (void)in_sizes; (void)n_in; (void)out_size; (void)ws_size;
    const float* x     = (const float*)d_in[0];
    const float* g     = (const float*)d_in[1];
    const float* w_qkv = (const float*)d_in[2];
    const float* dwq   = (const float*)d_in[3];
    const float* dwk   = (const float*)d_in[4];
    const float* dwv   = (const float*)d_in[5];
    const float* w_out = (const float*)d_in[6];
    const float* b_out = (const float*)d_in[7];
    float* out = (float*)d_out;

    char* ws = (char*)d_ws;
    size_t off = 0;
    auto alloc = [&](size_t nbytes) -> float* {
        char* p = ws + off;
        off = (off + nbytes + 255) & ~(size_t)255;
        return (float*)p;
    };
    float* wg   = alloc((size_t)QKV3 * C_IN * 4);
    float* wsum = alloc((size_t)QKV3 * 4);
    float* mean = alloc((size_t)BATCH * SS * 4);
    float* rstd = alloc((size_t)BATCH * SS * 4);
    float* cosT = alloc((size_t)SS * 32 * 4);
    float* sinT = alloc((size_t)SS * 32 * 4);
    float* qkv  = alloc((size_t)BATCH * QKV3 * SS * 4);
    float* seq  = alloc((size_t)3 * BATCH * HEADS * SS * DH * 4);
    float* O    = qkv;  // qkv buffer is dead after conv_rope; reuse for attention output

    prep_wg<<<QKV3, 256, 0, stream>>>(w_qkv, g, wg, wsum);
    prep_rope<<<288, 256, 0, stream>>>(cosT, sinT);
    prep_stats<<<36, 256, 0, stream>>>(x, mean, rstd);
    qkv_gemm<<<dim3(18, 12, BATCH), 256, 0, stream>>>(x, wg, wsum, mean, rstd, qkv);
    conv_rope<<<dim3(36, 24, BATCH), 256, 0, stream>>>(qkv, dwq, dwk, dwv, cosT, sinT, seq);
    attn<<<dim3(36, 32), 256, 0, stream>>>(seq, O);
    outproj<<<dim3(18, 4, BATCH), 256, 0, stream>>>(O, w_out, b_out, out);
}

// Round 2
// 972.516 us; speedup vs baseline: 1.2540x; 1.2540x over previous
//
#include <hip/hip_runtime.h>
#include <math.h>

#define SS 2304
#define C_IN 256
#define HID 512
#define QKV3 1536
#define HEADS 8
#define DH 64
#define BATCH 4
#define EPSV 1e-5f
#define SCALEV 0.125f

typedef short s8v __attribute__((ext_vector_type(8)));
typedef float f4v __attribute__((ext_vector_type(4)));

static __device__ inline unsigned short f2bf(float x) {
    unsigned int u = __float_as_uint(x);
    u += 0x7fffu + ((u >> 16) & 1u);
    return (unsigned short)(u >> 16);
}
static __device__ inline float bf2f(unsigned short h) {
    return __uint_as_float((unsigned int)h << 16);
}

static __device__ inline f4v mm(s8v a, s8v b, f4v c) {
    return __builtin_amdgcn_mfma_f32_16x16x32_bf16(a, b, c, 0, 0, 0);
}

// ---------------- prep: wg = w_qkv * g, wsum[o] = sum_c wg ----------------
__global__ void prep_wg(const float* __restrict__ w, const float* __restrict__ g,
                        float* __restrict__ wg, float* __restrict__ wsum) {
    __shared__ float red[256];
    int o = blockIdx.x, c = threadIdx.x;
    float v = w[o * C_IN + c] * g[c];
    wg[o * C_IN + c] = v;
    red[c] = v;
    __syncthreads();
    for (int st = 128; st > 0; st >>= 1) {
        if (c < st) red[c] += red[c + st];
        __syncthreads();
    }
    if (c == 0) wsum[o] = red[0];
}

// ---------------- prep: RoPE tables in double precision ----------------
__global__ void prep_rope(float* __restrict__ cosT, float* __restrict__ sinT) {
    int idx = blockIdx.x * 256 + threadIdx.x;
    if (idx >= SS * 32) return;
    int s = idx >> 5, f = idx & 31;
    double inv = pow(10000.0, -(double)f / 32.0);
    double ang = (double)s * inv;
    cosT[idx] = (float)cos(ang);
    sinT[idx] = (float)sin(ang);
}

// ---------------- prep: per-pixel mean / rstd over C ----------------
__global__ void prep_stats(const float* __restrict__ x, float* __restrict__ mean,
                           float* __restrict__ rstd) {
    int p = blockIdx.x * 256 + threadIdx.x;  // 0..9215
    int b = p / SS, s = p % SS;
    const float* xp = x + (size_t)b * C_IN * SS + s;
    float sm = 0.f;
    for (int c = 0; c < C_IN; ++c) sm += xp[(size_t)c * SS];
    float mu = sm * (1.0f / C_IN);
    float vs = 0.f;
    for (int c = 0; c < C_IN; ++c) { float d = xp[(size_t)c * SS] - mu; vs += d * d; }
    mean[p] = mu;
    rstd[p] = rsqrtf(vs * (1.0f / C_IN) + EPSV);
}

// ---------------- QKV GEMM with folded layernorm ----------------
__global__ __launch_bounds__(256) void qkv_gemm(
    const float* __restrict__ x, const float* __restrict__ wg,
    const float* __restrict__ wsum, const float* __restrict__ mean,
    const float* __restrict__ rstd, float* __restrict__ qkv) {
    __shared__ float As[16][132];
    __shared__ float Bs[16][132];
    int b = blockIdx.z;
    int m0 = blockIdx.y * 128;
    int n0 = blockIdx.x * 128;
    int t = threadIdx.x;
    int tx = t & 15, ty = t >> 4;
    float acc[8][8] = {};
    const float* xb = x + (size_t)b * C_IN * SS;
    for (int k0 = 0; k0 < C_IN; k0 += 16) {
#pragma unroll
        for (int i = 0; i < 8; ++i) {
            int idx = t + i * 256;
            int kk = idx & 15, row = idx >> 4;
            As[kk][row] = wg[(m0 + row) * C_IN + k0 + kk];
            int ssi = idx & 127, cc = idx >> 7;
            Bs[cc][ssi] = xb[(size_t)(k0 + cc) * SS + n0 + ssi];
        }
        __syncthreads();
#pragma unroll
        for (int kk = 0; kk < 16; ++kk) {
            float4 a0 = *(const float4*)&As[kk][ty * 8];
            float4 a1 = *(const float4*)&As[kk][ty * 8 + 4];
            float4 b0 = *(const float4*)&Bs[kk][tx * 8];
            float4 b1 = *(const float4*)&Bs[kk][tx * 8 + 4];
            float am[8] = {a0.x, a0.y, a0.z, a0.w, a1.x, a1.y, a1.z, a1.w};
            float bn[8] = {b0.x, b0.y, b0.z, b0.w, b1.x, b1.y, b1.z, b1.w};
#pragma unroll
            for (int r = 0; r < 8; ++r)
#pragma unroll
                for (int c = 0; c < 8; ++c) acc[r][c] += am[r] * bn[c];
        }
        __syncthreads();
    }
    float mnv[8], rsv[8];
#pragma unroll
    for (int c = 0; c < 8; ++c) {
        int n = n0 + tx * 8 + c;
        mnv[c] = mean[b * SS + n];
        rsv[c] = rstd[b * SS + n];
    }
#pragma unroll
    for (int r = 0; r < 8; ++r) {
        int m = m0 + ty * 8 + r;
        float ws = wsum[m];
        float* dst = qkv + ((size_t)b * QKV3 + m) * SS + n0 + tx * 8;
        float ov[8];
#pragma unroll
        for (int c = 0; c < 8; ++c) ov[c] = rsv[c] * (acc[r][c] - mnv[c] * ws);
        *(float4*)dst = make_float4(ov[0], ov[1], ov[2], ov[3]);
        *(float4*)(dst + 4) = make_float4(ov[4], ov[5], ov[6], ov[7]);
    }
}

// ------- dwconv 3x3 + RoPE + hi/lo bf16 split.  Q,K: [bh][s][d]; V: [bh][d][s] -------
__global__ __launch_bounds__(256) void conv_rope(
    const float* __restrict__ qkv, const float* __restrict__ dwq,
    const float* __restrict__ dwk, const float* __restrict__ dwv,
    const float* __restrict__ cosT, const float* __restrict__ sinT,
    unsigned short* __restrict__ qhi, unsigned short* __restrict__ qlo,
    unsigned short* __restrict__ khi, unsigned short* __restrict__ klo,
    unsigned short* __restrict__ vthi, unsigned short* __restrict__ vtlo) {
    __shared__ float tile[64][65];
    int b = blockIdx.z;
    int part = blockIdx.y >> 3;
    int h = blockIdx.y & 7;
    int s0 = blockIdx.x * 64;
    int t = threadIdx.x;
    int sl = t & 63, dgrp = t >> 6;
    int s = s0 + sl;
    int y = s / 48, xx = s - y * 48;
    int bh = b * HEADS + h;
    const float* dw = (part == 0) ? dwq : (part == 1) ? dwk : dwv;
#pragma unroll
    for (int i = 0; i < 16; ++i) {
        int d = dgrp * 16 + i;
        int cch = part * HID + h * DH + d;
        const float* src = qkv + ((size_t)b * QKV3 + cch) * SS;
        const float* wp = dw + (h * DH + d) * 9;
        float acc = 0.f;
#pragma unroll
        for (int dy = -1; dy <= 1; ++dy) {
            int yy = y + dy;
            if (yy < 0 || yy >= 48) continue;
#pragma unroll
            for (int dx = -1; dx <= 1; ++dx) {
                int xv = xx + dx;
                if (xv < 0 || xv >= 48) continue;
                acc += wp[(dy + 1) * 3 + (dx + 1)] * src[yy * 48 + xv];
            }
        }
        if (part == 2) {
            size_t o = ((size_t)bh * DH + d) * SS + s;
            unsigned short hu = f2bf(acc);
            vthi[o] = hu;
            vtlo[o] = f2bf(acc - bf2f(hu));
        } else {
            tile[d][sl] = acc;
        }
    }
    if (part == 2) return;
    __syncthreads();
    int d2 = t & 63, srow = t >> 6;
    unsigned short* hiA = (part == 0) ? qhi : khi;
    unsigned short* loA = (part == 0) ? qlo : klo;
#pragma unroll
    for (int i = 0; i < 16; ++i) {
        int sp = srow + 4 * i;
        float v0 = tile[d2][sp];
        float vp = tile[d2 ^ 32][sp];
        int f = d2 & 31;
        float cv = cosT[(s0 + sp) * 32 + f];
        float sv = sinT[(s0 + sp) * 32 + f];
        float rot = (d2 < 32) ? -vp : vp;
        float val = v0 * cv + rot * sv;
        if (part == 0) val *= SCALEV;
        size_t o = ((size_t)bh * SS + s0 + sp) * DH + d2;
        unsigned short hu = f2bf(val);
        hiA[o] = hu;
        loA[o] = f2bf(val - bf2f(hu));
    }
}

// ---------------- flash attention: hi/lo bf16 MFMA, online softmax ----------------
__global__ __launch_bounds__(256) void attn_mfma(
    const unsigned short* __restrict__ qhi, const unsigned short* __restrict__ qlo,
    const unsigned short* __restrict__ khi, const unsigned short* __restrict__ klo,
    const unsigned short* __restrict__ vthi, const unsigned short* __restrict__ vtlo,
    float* __restrict__ O) {
    __shared__ unsigned short pb[4][2][16][72];  // per-wave P transpose buffers
    int bh = blockIdx.y;
    int i0 = blockIdx.x * 64;
    int t = threadIdx.x;
    int wv = t >> 6;
    int lane = t & 63;
    int l15 = lane & 15;
    int quad = lane >> 4;

    // Q fragments: A[m=l15][k=quad*8+j], k split in two 32-chunks
    const size_t qb = ((size_t)bh * SS + i0 + wv * 16 + l15) * DH + quad * 8;
    s8v qh0 = *(const s8v*)(qhi + qb);
    s8v qh1 = *(const s8v*)(qhi + qb + 32);
    s8v ql0 = *(const s8v*)(qlo + qb);
    s8v ql1 = *(const s8v*)(qlo + qb + 32);

    f4v oacc[4];
#pragma unroll
    for (int nt = 0; nt < 4; ++nt) oacc[nt] = (f4v){0.f, 0.f, 0.f, 0.f};
    float mrow[4], lrow[4];
#pragma unroll
    for (int r = 0; r < 4; ++r) { mrow[r] = -INFINITY; lrow[r] = 0.f; }

    const size_t kbh = (size_t)bh * SS * DH;
    const size_t vbh = (size_t)bh * DH * SS;

    for (int jt = 0; jt < 36; ++jt) {
        int j0 = jt * 64;
        f4v sv4[4];
#pragma unroll
        for (int nt = 0; nt < 4; ++nt) sv4[nt] = (f4v){0.f, 0.f, 0.f, 0.f};
        // ---- QK^T: B-frag of K is K row-major (n=j in l15, k=d in quad) ----
#pragma unroll
        for (int nt = 0; nt < 4; ++nt) {
            size_t kb = kbh + (size_t)(j0 + nt * 16 + l15) * DH + quad * 8;
            s8v k0h = *(const s8v*)(khi + kb);
            s8v k1h = *(const s8v*)(khi + kb + 32);
            s8v k0l = *(const s8v*)(klo + kb);
            s8v k1l = *(const s8v*)(klo + kb + 32);
            sv4[nt] = mm(qh0, k0h, sv4[nt]);
            sv4[nt] = mm(qh1, k1h, sv4[nt]);
            sv4[nt] = mm(ql0, k0h, sv4[nt]);
            sv4[nt] = mm(ql1, k1h, sv4[nt]);
            sv4[nt] = mm(qh0, k0l, sv4[nt]);
            sv4[nt] = mm(qh1, k1l, sv4[nt]);
        }
        // ---- V fragments (issued early; consumed after softmax) ----
        s8v vh[4][2], vl[4][2];
#pragma unroll
        for (int nt = 0; nt < 4; ++nt) {
            size_t vb = vbh + (size_t)(nt * 16 + l15) * SS + j0 + quad * 8;
            vh[nt][0] = *(const s8v*)(vthi + vb);
            vh[nt][1] = *(const s8v*)(vthi + vb + 32);
            vl[nt][0] = *(const s8v*)(vtlo + vb);
            vl[nt][1] = *(const s8v*)(vtlo + vb + 32);
        }
        // ---- online softmax; rows i = quad*4+r, cols j = nt*16+l15 ----
#pragma unroll
        for (int r = 0; r < 4; ++r) {
            float mx = fmaxf(fmaxf(sv4[0][r], sv4[1][r]), fmaxf(sv4[2][r], sv4[3][r]));
            mx = fmaxf(mx, __shfl_xor(mx, 1));
            mx = fmaxf(mx, __shfl_xor(mx, 2));
            mx = fmaxf(mx, __shfl_xor(mx, 4));
            mx = fmaxf(mx, __shfl_xor(mx, 8));
            float mn = fmaxf(mrow[r], mx);
            float al = __expf(mrow[r] - mn);
            mrow[r] = mn;
            lrow[r] *= al;
#pragma unroll
            for (int nt = 0; nt < 4; ++nt) oacc[nt][r] *= al;
            float rs = 0.f;
#pragma unroll
            for (int nt = 0; nt < 4; ++nt) {
                float p = __expf(sv4[nt][r] - mn);
                rs += p;
                unsigned short phu = f2bf(p);
                pb[wv][0][quad * 4 + r][nt * 16 + l15] = phu;
                pb[wv][1][quad * 4 + r][nt * 16 + l15] = f2bf(p - bf2f(phu));
            }
            rs += __shfl_xor(rs, 1);
            rs += __shfl_xor(rs, 2);
            rs += __shfl_xor(rs, 4);
            rs += __shfl_xor(rs, 8);
            lrow[r] += rs;
        }
        // ---- read P back in A-layout (wave-private buffer; compiler inserts lgkm waits)
        s8v ph0 = *(const s8v*)&pb[wv][0][l15][quad * 8];
        s8v ph1 = *(const s8v*)&pb[wv][0][l15][32 + quad * 8];
        s8v pl0 = *(const s8v*)&pb[wv][1][l15][quad * 8];
        s8v pl1 = *(const s8v*)&pb[wv][1][l15][32 + quad * 8];
        // ---- PV ----
#pragma unroll
        for (int nt = 0; nt < 4; ++nt) {
            oacc[nt] = mm(ph0, vh[nt][0], oacc[nt]);
            oacc[nt] = mm(ph1, vh[nt][1], oacc[nt]);
            oacc[nt] = mm(pl0, vh[nt][0], oacc[nt]);
            oacc[nt] = mm(pl1, vh[nt][1], oacc[nt]);
            oacc[nt] = mm(ph0, vl[nt][0], oacc[nt]);
            oacc[nt] = mm(ph1, vl[nt][1], oacc[nt]);
        }
    }
    // ---- epilogue: C-layout rows i=quad*4+r, cols d=nt*16+l15 ----
#pragma unroll
    for (int r = 0; r < 4; ++r) {
        float inv = 1.f / lrow[r];
        size_t ob = ((size_t)bh * SS + i0 + wv * 16 + quad * 4 + r) * DH;
#pragma unroll
        for (int nt = 0; nt < 4; ++nt) O[ob + nt * 16 + l15] = oacc[nt][r] * inv;
    }
}

// ---------------- output projection + bias ----------------
__global__ __launch_bounds__(256) void outproj(
    const float* __restrict__ O, const float* __restrict__ w_out,
    const float* __restrict__ b_out, float* __restrict__ out) {
    __shared__ float As[16][68];
    __shared__ float Bs[16][132];
    int b = blockIdx.z;
    int m0 = blockIdx.y * 64;
    int n0 = blockIdx.x * 128;
    int t = threadIdx.x;
    int tx = t & 15, ty = t >> 4;
    float acc[4][8] = {};
    for (int k0 = 0; k0 < HID; k0 += 16) {
        int h = k0 >> 6, d0 = k0 & 63;
        const float* Ob = O + ((size_t)(b * HEADS + h) * SS + n0) * DH + d0;
#pragma unroll
        for (int i = 0; i < 4; ++i) {
            int idx = t + i * 256;
            int kk = idx & 15, mm2 = idx >> 4;
            As[kk][mm2] = w_out[(m0 + mm2) * HID + k0 + kk];
        }
#pragma unroll
        for (int i = 0; i < 8; ++i) {
            int idx = t + i * 256;
            int kk = idx & 15, nn = idx >> 4;
            Bs[kk][nn] = Ob[(size_t)nn * DH + kk];
        }
        __syncthreads();
#pragma unroll
        for (int kk = 0; kk < 16; ++kk) {
            float4 av = *(const float4*)&As[kk][ty * 4];
            float4 b0 = *(const float4*)&Bs[kk][tx * 8];
            float4 b1 = *(const float4*)&Bs[kk][tx * 8 + 4];
            float aa[4] = {av.x, av.y, av.z, av.w};
            float bb[8] = {b0.x, b0.y, b0.z, b0.w, b1.x, b1.y, b1.z, b1.w};
#pragma unroll
            for (int r = 0; r < 4; ++r)
#pragma unroll
                for (int c = 0; c < 8; ++c) acc[r][c] += aa[r] * bb[c];
        }
        __syncthreads();
    }
#pragma unroll
    for (int r = 0; r < 4; ++r) {
        int o = m0 + ty * 4 + r;
        float bo = b_out[o];
        float* dst = out + ((size_t)b * C_IN + o) * SS + n0 + tx * 8;
        float ov[8];
#pragma unroll
        for (int c = 0; c < 8; ++c) ov[c] = acc[r][c] + bo;
        *(float4*)dst = make_float4(ov[0], ov[1], ov[2], ov[3]);
        *(float4*)(dst + 4) = make_float4(ov[4], ov[5], ov[6], ov[7]);
    }
}

extern "C" void kernel_launch(void* const* d_in, const int* in_sizes, int n_in,
                              void* d_out, int out_size, void* d_ws, size_t ws_size,
                              hipStream_t stream) {
    (void)in_sizes; (void)n_in; (void)out_size; (void)ws_size;
    const float* x     = (const float*)d_in[0];
    const float* g     = (const float*)d_in[1];
    const float* w_qkv = (const float*)d_in[2];
    const float* dwq   = (const float*)d_in[3];
    const float* dwk   = (const float*)d_in[4];
    const float* dwv   = (const float*)d_in[5];
    const float* w_out = (const float*)d_in[6];
    const float* b_out = (const float*)d_in[7];
    float* out = (float*)d_out;

    char* ws = (char*)d_ws;
    size_t off = 0;
    auto alloc = [&](size_t nbytes) -> void* {
        char* p = ws + off;
        off = (off + nbytes + 255) & ~(size_t)255;
        return (void*)p;
    };
    const size_t NSD = (size_t)BATCH * HEADS * SS * DH;  // 4.7M elements
    float* wg   = (float*)alloc((size_t)QKV3 * C_IN * 4);
    float* wsum = (float*)alloc((size_t)QKV3 * 4);
    float* mean = (float*)alloc((size_t)BATCH * SS * 4);
    float* rstd = (float*)alloc((size_t)BATCH * SS * 4);
    float* cosT = (float*)alloc((size_t)SS * 32 * 4);
    float* sinT = (float*)alloc((size_t)SS * 32 * 4);
    float* qkv  = (float*)alloc((size_t)BATCH * QKV3 * SS * 4);
    unsigned short* qhi  = (unsigned short*)alloc(NSD * 2);
    unsigned short* qlo  = (unsigned short*)alloc(NSD * 2);
    unsigned short* khi  = (unsigned short*)alloc(NSD * 2);
    unsigned short* klo  = (unsigned short*)alloc(NSD * 2);
    unsigned short* vthi = (unsigned short*)alloc(NSD * 2);
    unsigned short* vtlo = (unsigned short*)alloc(NSD * 2);
    float* O = qkv;  // qkv buffer dead after conv_rope; reuse for attention output

    prep_wg<<<QKV3, 256, 0, stream>>>(w_qkv, g, wg, wsum);
    prep_rope<<<288, 256, 0, stream>>>(cosT, sinT);
    prep_stats<<<36, 256, 0, stream>>>(x, mean, rstd);
    qkv_gemm<<<dim3(18, 12, BATCH), 256, 0, stream>>>(x, wg, wsum, mean, rstd, qkv);
    conv_rope<<<dim3(36, 24, BATCH), 256, 0, stream>>>(qkv, dwq, dwk, dwv, cosT, sinT,
                                                       qhi, qlo, khi, klo, vthi, vtlo);
    attn_mfma<<<dim3(36, 32), 256, 0, stream>>>(qhi, qlo, khi, klo, vthi, vtlo, O);
    outproj<<<dim3(18, 4, BATCH), 256, 0, stream>>>(O, w_out, b_out, out);
}